// Round 7
// baseline (239.001 us; speedup 1.0000x reference)
//
#include <hip/hip_runtime.h>
#include <hip/hip_fp16.h>
#include <math.h>

#define DIM 128
#define TR 32         // nodes per fused block
#define SA_STRIDE 136 // bf16 elements per sA row (128 + 8 pad, keeps 16B alignment)

#define DEG_SHIFT 42          // cnt in bits 42..63 of packed u64
#define DEG_SCALE 33554432.0f // 2^25 fixed-point scale for deg
#define DEG_MASK ((1ull << DEG_SHIFT) - 1)

typedef __attribute__((ext_vector_type(8))) short bf16x8;  // also used as generic 8x16b
typedef __attribute__((ext_vector_type(4))) float f32x4;

__device__ __forceinline__ ushort f2bf(float f) {
    union { float f; unsigned u; } v; v.f = f;
    unsigned u = v.u;
    return (ushort)((u + 0x7FFFu + ((u >> 16) & 1u)) >> 16);  // RNE
}

__device__ __forceinline__ ushort f2h(float f) {
    __half h = __float2half_rn(f);                 // v_cvt_f16_f32 (RNE)
    return *reinterpret_cast<ushort*>(&h);
}

__device__ __forceinline__ float h2f(ushort u) {
    __half_raw hr; hr.x = u;
    return __half2float(__half(hr));               // v_cvt_f32_f16
}

__global__ void fill_zero(float* p, int n) {
    int i = blockIdx.x * blockDim.x + threadIdx.x;
    if (i < n) p[i] = 0.f;
}

__global__ void fill_zero4(float4* p, int n4) {
    int i = blockIdx.x * blockDim.x + threadIdx.x;
    if (i < n4) p[i] = make_float4(0.f, 0.f, 0.f, 0.f);
}

// Fused init: xh = fp16(x) (nxh threads, 8 elems each — fp16 keeps 10 mantissa
// bits, 8x below the pipeline's existing bf16 rounding, so absmax is unchanged
// while random gather rows halve to 256B); Wt[n][k] = bf16(W[k][n]); zero cd;
// reset gctr.
__global__ void init_kernel(const float* __restrict__ W, ushort* __restrict__ Wt,
                            const float* __restrict__ x, ushort* __restrict__ xh, int nxh,
                            float* __restrict__ zbase, int nz, int* __restrict__ gctr) {
    int i = blockIdx.x * blockDim.x + threadIdx.x;
    if (i < nxh) {
        const float4* xs = (const float4*)x;
        float4 a = xs[i * 2], c = xs[i * 2 + 1];
        bf16x8 h;
        h[0] = (short)f2h(a.x); h[1] = (short)f2h(a.y);
        h[2] = (short)f2h(a.z); h[3] = (short)f2h(a.w);
        h[4] = (short)f2h(c.x); h[5] = (short)f2h(c.y);
        h[6] = (short)f2h(c.z); h[7] = (short)f2h(c.w);
        *(bf16x8*)&xh[i * 8] = h;                  // 16B store
    }
    int j = i - nxh;
    if (j >= 0 && j < 16384) {
        int k = j >> 7, n = j & 127;
        Wt[n * DIM + k] = f2bf(W[k * DIM + n]);
    }
    int z = i - nxh - 16384;
    if (z >= 0 && z < nz) zbase[z] = 0.f;
    if (i == 0) *gctr = 0;
}

// ONE u64 atomic per edge: cd[col] += (1<<42) | round(ew * 2^25).
// The RETURNED old value's cnt field is this edge's arrival rank within its
// node — recorded to rank[e] (coalesced write), which makes csr_fill atomic-free.
__global__ void count_deg_kernel(const int* __restrict__ ei, const float* __restrict__ ew,
                                 unsigned long long* __restrict__ cd,
                                 int* __restrict__ rank, int E) {
    int e = blockIdx.x * blockDim.x + threadIdx.x;
    if (e < E) {
        int col = ei[E + e];
        unsigned long long pk = (1ull << DEG_SHIFT)
                              + (unsigned long long)(ew[e] * DEG_SCALE + 0.5f);
        unsigned long long old = atomicAdd(&cd[col], pk);
        rank[e] = (int)(old >> DEG_SHIFT);
    }
}

// Segment allocation: wave-level inclusive scan of cnt, block-level combine in LDS,
// ONE atomicAdd per BLOCK on gctr (per-wave hot-line version serialized cross-XCD).
// Nodes within a block (256 consecutive ids) get contiguous, ordered segments.
// Writes row_start, row_end (= start + cnt) and dinv from the packed deg.
__global__ __launch_bounds__(256) void alloc_kernel(const unsigned long long* __restrict__ cd,
                                                    float* __restrict__ dinv,
                                                    int* __restrict__ row_start,
                                                    int* __restrict__ row_end,
                                                    int* __restrict__ gctr, int N) {
    __shared__ int wsum[4];
    __shared__ int sbase;
    int t = threadIdx.x;
    int i = blockIdx.x * 256 + t;
    int lane = t & 63;
    int w = t >> 6;
    unsigned long long p = (i < N) ? cd[i] : 0ull;
    int c = (int)(p >> DEG_SHIFT);
    int pre = c;
#pragma unroll
    for (int off = 1; off < 64; off <<= 1) {
        int v = __shfl_up(pre, off);
        if (lane >= off) pre += v;
    }
    if (lane == 63) wsum[w] = pre;
    __syncthreads();
    if (t == 0) sbase = atomicAdd(gctr, wsum[0] + wsum[1] + wsum[2] + wsum[3]);
    __syncthreads();
    int woff = 0;
#pragma unroll
    for (int k = 0; k < 3; ++k) if (w > k) woff += wsum[k];
    if (i < N) {
        int rs = sbase + woff + pre - c;   // exclusive prefix within block + block base
        row_start[i] = rs;
        row_end[i] = rs + c;
        float d = (float)(p & DEG_MASK) * (1.0f / DEG_SCALE);
        dinv[i] = d > 0.f ? rsqrtf(d) : 0.f;
    }
}

// CSR fill, ATOMIC-FREE: p = row_start[col] + rank[e]; csr[p] = {row, bits(dinv[row]*ew)}.
// Per edge: two random READS (row_start[col], dinv[row] — no RMW ping-pong) and one
// random 8B write. dinv[row] lives HERE, not in the gather (round 5: per-edge dinv
// load in the gather cost ~20 us via load-queue pressure / occupancy 46->38%).
__global__ void csr_fill_kernel(const int* __restrict__ ei, const float* __restrict__ ew,
                                const int* __restrict__ rank,
                                const int* __restrict__ row_start,
                                const float* __restrict__ dinv,
                                int2* __restrict__ csr, int E) {
    int e = blockIdx.x * blockDim.x + threadIdx.x;
    if (e < E) {
        int row = ei[e];
        int col = ei[E + e];
        int p = row_start[col] + rank[e];
        float w = dinv[row] * ew[e];
        csr[p] = make_int2(row, __float_as_int(w));
    }
}

// Fused: CSR gather -> LDS bf16 -> MFMA 32x128 @ 128x128 -> bias+LN+GELU+residual.
// 256 threads = 4 waves. Gather: 8 groups of 32 lanes, 4 nodes each, ROUND-ROBIN,
// unroll 2 -> 8 independent csr->x chains/group. unroll 4 REGRESSED (occupancy
// 30%); per-edge extra load REGRESSED (occupancy 38%): exactly ONE row load per
// edge chain, VGPR <= ~52. XH=true reads fp16-staged rows (256B vs 512B — the
// gather runs at memory-path throughput ~66 cy/512B-slot, so bytes are the lever).
// Invalid slots predicated (clamp to csr[0], weight 0). Residual reads fp32 x.
// GEMM: wave w -> row-tile tm=w&1 (16 rows), col-tiles tn = 4*(w>>1)..+3 (64 cols).
template<bool XH>
__global__ __launch_bounds__(256) void gather_mfma_ln_kernel(
        const int2* __restrict__ csr, const int* __restrict__ row_start,
        const int* __restrict__ seg_end, const float* __restrict__ dinv,
        const float* __restrict__ x, const ushort* __restrict__ xh,
        const ushort* __restrict__ Wt, const float* __restrict__ b,
        const float* __restrict__ gamma, const float* __restrict__ beta,
        float* __restrict__ out, int N) {
    __shared__ ushort sA[TR * SA_STRIDE];  // 8.5 KB bf16 agg tile
    __shared__ float redS[4][16];
    __shared__ float redQ[4][16];

    const int tid  = threadIdx.x;
    const int l32  = tid & 31;
    const int g32  = tid >> 5;       // gather group 0..7
    const int lane = tid & 63;
    const int w    = tid >> 6;       // wave 0..3
    const int row0 = blockIdx.x * TR;

    // ---- Phase A: round-robin gather, 4 nodes per 32-lane group ----
    const float4* xv = (const float4*)x;
    const ushort4* xhv = (const ushort4*)xh;
    int sidx[4], eidx[4];
    float dv[4];
    float4 accq[4];
    int maxlen = 0;
#pragma unroll
    for (int q = 0; q < 4; ++q) {
        int node = row0 + g32 * 4 + q;
        int ok = node < N;
        sidx[q] = ok ? row_start[node] : 0;
        eidx[q] = ok ? seg_end[node] : 0;
        dv[q]   = ok ? dinv[node] : 0.f;
        accq[q] = make_float4(0.f, 0.f, 0.f, 0.f);
        int len = eidx[q] - sidx[q];
        maxlen = len > maxlen ? len : maxlen;
    }
    // maxlen is group-uniform (node ids are group-uniform)
#pragma unroll 2
    for (int it = 0; it < maxlen; ++it) {
        int2 pk[4];
#pragma unroll
        for (int q = 0; q < 4; ++q) {
            int j = sidx[q] + it;
            pk[q] = csr[j < eidx[q] ? j : 0];   // predicated slot, always-valid addr
        }
#pragma unroll
        for (int q = 0; q < 4; ++q) {
            float wt = (sidx[q] + it < eidx[q]) ? __int_as_float(pk[q].y) : 0.f;
            float4 v;
            if (XH) {
                ushort4 hv = xhv[(size_t)pk[q].x * 32 + l32];   // 8B/lane, 256B/row
                v = make_float4(h2f(hv.x), h2f(hv.y), h2f(hv.z), h2f(hv.w));
            } else {
                v = xv[(size_t)pk[q].x * 32 + l32];             // 16B/lane, 512B/row
            }
            accq[q].x += wt * v.x; accq[q].y += wt * v.y;
            accq[q].z += wt * v.z; accq[q].w += wt * v.w;
        }
    }
#pragma unroll
    for (int q = 0; q < 4; ++q) {
        int r = g32 * 4 + q;
        ushort4 p4;
        p4.x = f2bf(accq[q].x * dv[q]); p4.y = f2bf(accq[q].y * dv[q]);
        p4.z = f2bf(accq[q].z * dv[q]); p4.w = f2bf(accq[q].w * dv[q]);
        *(ushort4*)&sA[r * SA_STRIDE + l32 * 4] = p4;   // ds_write_b64, conflict-free
    }
    __syncthreads();

    // ---- Phase B: MFMA GEMM ----
    const int m16  = lane & 15;
    const int quad = lane >> 4;          // 0..3
    const int tm   = w & 1;              // row-tile
    const int tnb  = (w >> 1) * 4;       // first col-tile

    bf16x8 afrag[4];
    const ushort* arow = &sA[(16 * tm + m16) * SA_STRIDE + quad * 8];
#pragma unroll
    for (int kb = 0; kb < 4; ++kb)
        afrag[kb] = *(const bf16x8*)(arow + kb * 32);   // ds_read_b128

    f32x4 acc[4];
#pragma unroll
    for (int t = 0; t < 4; ++t) { acc[t][0] = 0.f; acc[t][1] = 0.f; acc[t][2] = 0.f; acc[t][3] = 0.f; }

#pragma unroll
    for (int kb = 0; kb < 4; ++kb) {
#pragma unroll
        for (int t = 0; t < 4; ++t) {
            const ushort* bp = Wt + (size_t)((tnb + t) * 16 + m16) * DIM + kb * 32 + quad * 8;
            bf16x8 bfrag = *(const bf16x8*)bp;          // global 16B, L1-resident
            acc[t] = __builtin_amdgcn_mfma_f32_16x16x32_bf16(afrag[kb], bfrag, acc[t], 0, 0, 0);
        }
    }

    // ---- bias (per col) before LN stats ----
    float gcol[4], becol[4];
#pragma unroll
    for (int t = 0; t < 4; ++t) {
        int col = (tnb + t) * 16 + m16;
        float bc = b[col];
        gcol[t]  = gamma[col];
        becol[t] = beta[col];
#pragma unroll
        for (int i = 0; i < 4; ++i) acc[t][i] += bc;
    }

    // ---- LN stats: rows 4*quad+i; reduce over this wave's 64 cols via quad shuffles ----
    float s[4], sq[4];
#pragma unroll
    for (int i = 0; i < 4; ++i) {
        s[i]  = acc[0][i] + acc[1][i] + acc[2][i] + acc[3][i];
        sq[i] = acc[0][i]*acc[0][i] + acc[1][i]*acc[1][i] + acc[2][i]*acc[2][i] + acc[3][i]*acc[3][i];
    }
#pragma unroll
    for (int off = 1; off <= 8; off <<= 1) {
#pragma unroll
        for (int i = 0; i < 4; ++i) {
            s[i]  += __shfl_xor(s[i], off);
            sq[i] += __shfl_xor(sq[i], off);
        }
    }
    if (m16 == 0) {
#pragma unroll
        for (int i = 0; i < 4; ++i) {
            redS[w][quad * 4 + i] = s[i];
            redQ[w][quad * 4 + i] = sq[i];
        }
    }
    __syncthreads();

    // ---- finish LN + GELU + residual, store ----
#pragma unroll
    for (int i = 0; i < 4; ++i) {
        int rloc = quad * 4 + i;
        float tot  = redS[w][rloc] + redS[w ^ 2][rloc];   // partner wave shares tm
        float totq = redQ[w][rloc] + redQ[w ^ 2][rloc];
        float mu   = tot * (1.0f / DIM);
        float var  = totq * (1.0f / DIM) - mu * mu;
        float rstd = rsqrtf(var + 1e-5f);
        int r = row0 + 16 * tm + rloc;
        if (r < N) {
#pragma unroll
            for (int t = 0; t < 4; ++t) {
                int col = (tnb + t) * 16 + m16;
                float l = (acc[t][i] - mu) * rstd * gcol[t] + becol[t];
                float g = 0.5f * l * (1.0f + erff(l * 0.70710678118654752f));
                out[(size_t)r * DIM + col] = x[(size_t)r * DIM + col] + g;
            }
        }
    }
}

// ---------------- fallback path (small workspace): atomic scatter + fp32 gemm_ln ----------------
__global__ void deg_kernel(const int* __restrict__ ei, const float* __restrict__ ew,
                           float* __restrict__ deg, int E) {
    int e = blockIdx.x * blockDim.x + threadIdx.x;
    if (e < E) atomicAdd(&deg[ei[E + e]], ew[e]);
}

__global__ void dinv_kernel(float* deg, int N) {
    int i = blockIdx.x * blockDim.x + threadIdx.x;
    if (i < N) {
        float d = deg[i];
        deg[i] = d > 0.f ? rsqrtf(d) : 0.f;
    }
}

__global__ void scatter_kernel(const int* __restrict__ ei, const float* __restrict__ ew,
                               const float* __restrict__ dinv, const float* __restrict__ x,
                               float* __restrict__ out, int E) {
    int t = blockIdx.x * blockDim.x + threadIdx.x;
    int e = t >> 5;
    if (e >= E) return;
    int lane = t & 31;
    int row = ei[e];
    int col = ei[E + e];
    float w = dinv[row] * ew[e] * dinv[col];
    float4 v = *(const float4*)(x + (size_t)row * DIM + (lane << 2));
    float* dst = out + (size_t)col * DIM + (lane << 2);
    atomicAdd(dst + 0, v.x * w);
    atomicAdd(dst + 1, v.y * w);
    atomicAdd(dst + 2, v.z * w);
    atomicAdd(dst + 3, v.w * w);
}

__global__ __launch_bounds__(256) void gemm_ln_kernel(const float* __restrict__ x,
                                                      const float* __restrict__ W,
                                                      const float* __restrict__ b,
                                                      const float* __restrict__ gamma,
                                                      const float* __restrict__ beta,
                                                      float* __restrict__ out, int N) {
    __shared__ float sT[DIM][TR + 4];
    const int tid = threadIdx.x;
    const int row0 = blockIdx.x * TR;
    {
        int r = tid >> 3;
        int c0 = (tid & 7) << 4;
        int rr = row0 + r; if (rr > N - 1) rr = N - 1;
        const float4* src = (const float4*)(out + (size_t)rr * DIM + c0);
#pragma unroll
        for (int i = 0; i < 4; ++i) {
            float4 v = src[i];
            int c = c0 + i * 4;
            sT[c + 0][r] = v.x; sT[c + 1][r] = v.y; sT[c + 2][r] = v.z; sT[c + 3][r] = v.w;
        }
    }
    __syncthreads();
    const int tx = tid & 31;
    const int ty = tid >> 5;
    float acc[4][4] = {};
    const float4* Wv = (const float4*)W;
#pragma unroll 4
    for (int k = 0; k < DIM; ++k) {
        float4 wv = Wv[k * 32 + tx];
        float4 a  = *(const float4*)(&sT[k][ty * 4]);
        acc[0][0] += a.x * wv.x; acc[0][1] += a.x * wv.y; acc[0][2] += a.x * wv.z; acc[0][3] += a.x * wv.w;
        acc[1][0] += a.y * wv.x; acc[1][1] += a.y * wv.y; acc[1][2] += a.y * wv.z; acc[1][3] += a.y * wv.w;
        acc[2][0] += a.z * wv.x; acc[2][1] += a.z * wv.y; acc[2][2] += a.z * wv.z; acc[2][3] += a.z * wv.w;
        acc[3][0] += a.w * wv.x; acc[3][1] += a.w * wv.y; acc[3][2] += a.w * wv.z; acc[3][3] += a.w * wv.w;
    }
    float4 b4 = ((const float4*)b)[tx];
#pragma unroll
    for (int i = 0; i < 4; ++i) {
        acc[i][0] += b4.x; acc[i][1] += b4.y; acc[i][2] += b4.z; acc[i][3] += b4.w;
    }
    float4 g4  = ((const float4*)gamma)[tx];
    float4 be4 = ((const float4*)beta)[tx];
#pragma unroll
    for (int i = 0; i < 4; ++i) {
        float s  = acc[i][0] + acc[i][1] + acc[i][2] + acc[i][3];
        float sq = acc[i][0]*acc[i][0] + acc[i][1]*acc[i][1] + acc[i][2]*acc[i][2] + acc[i][3]*acc[i][3];
#pragma unroll
        for (int off = 16; off > 0; off >>= 1) {
            s  += __shfl_xor(s, off);
            sq += __shfl_xor(sq, off);
        }
        float mu   = s * (1.0f / DIM);
        float var  = sq * (1.0f / DIM) - mu * mu;
        float rstd = rsqrtf(var + 1e-5f);
        int r = row0 + ty * 4 + i;
        if (r < N) {
            float4 xr = *(const float4*)(x + (size_t)r * DIM + tx * 4);
            float lg[4] = {g4.x, g4.y, g4.z, g4.w};
            float lb[4] = {be4.x, be4.y, be4.z, be4.w};
            float lx[4] = {xr.x, xr.y, xr.z, xr.w};
            float o[4];
#pragma unroll
            for (int c = 0; c < 4; ++c) {
                float l = (acc[i][c] - mu) * rstd * lg[c] + lb[c];
                float g = 0.5f * l * (1.0f + erff(l * 0.70710678118654752f));
                o[c] = lx[c] + g;
            }
            *(float4*)(out + (size_t)r * DIM + tx * 4) = make_float4(o[0], o[1], o[2], o[3]);
        }
    }
}

extern "C" void kernel_launch(void* const* d_in, const int* in_sizes, int n_in,
                              void* d_out, int out_size, void* d_ws, size_t ws_size,
                              hipStream_t stream) {
    const float* x     = (const float*)d_in[0];
    const int*   ei    = (const int*)d_in[1];    // [2, E] int32
    const float* ew    = (const float*)d_in[2];
    const float* W     = (const float*)d_in[3];
    const float* b     = (const float*)d_in[4];
    const float* gamma = (const float*)d_in[5];
    const float* beta  = (const float*)d_in[6];
    const int N = in_sizes[0] / DIM;
    const int E = in_sizes[2];
    float* out = (float*)d_out;

    const int nb = (N + 255) / 256;

    // ws words: Wt bf16[128*128] (8192) | cd u64[N] (2N) | dinv[N] | row_start[N] |
    //           row_end[N] | rank[E] | gctr[1] | pad16B | [xh ushort[N*128]] | csr int2[E]
    size_t hdr_words = 8192 + (size_t)5 * N + (size_t)E + 1;
    hdr_words = (hdr_words + 3) & ~(size_t)3;          // 16B align for xh stores
    size_t xh_words = (size_t)N * (DIM / 2);           // fp16 copy of x
    size_t need_basic = (hdr_words + (size_t)2 * E) * sizeof(float);
    size_t need_xh    = (hdr_words + xh_words + (size_t)2 * E) * sizeof(float);

    if (ws_size >= need_basic) {
        const bool use_xh = (ws_size >= need_xh);
        ushort* Wt         = (ushort*)d_ws;
        unsigned long long* cd = (unsigned long long*)((float*)d_ws + 8192);
        float*  dinv       = (float*)d_ws + 8192 + (size_t)2 * N;
        int*    row_start  = (int*)(dinv + N);
        int*    row_end    = row_start + N;
        int*    rank       = row_end + N;
        int*    gctr       = rank + E;
        ushort* xh         = (ushort*)((float*)d_ws + hdr_words);
        int2*   csr        = (int2*)((float*)d_ws + hdr_words + (use_xh ? xh_words : 0));

        int nxh = use_xh ? N * (DIM / 8) : 0;          // threads converting 8 elems each
        int initn = nxh + 16384 + 2 * N;
        init_kernel<<<(initn + 255) / 256, 256, 0, stream>>>(W, Wt, x, xh, nxh,
                                                             (float*)cd, 2 * N, gctr);
        count_deg_kernel<<<(E + 255) / 256, 256, 0, stream>>>(ei, ew, cd, rank, E);
        alloc_kernel<<<nb, 256, 0, stream>>>(cd, dinv, row_start, row_end, gctr, N);
        csr_fill_kernel<<<(E + 255) / 256, 256, 0, stream>>>(ei, ew, rank, row_start, dinv, csr, E);

        if (use_xh) {
            gather_mfma_ln_kernel<true><<<(N + TR - 1) / TR, 256, 0, stream>>>(
                csr, row_start, row_end, dinv, x, xh, Wt, b, gamma, beta, out, N);
        } else {
            gather_mfma_ln_kernel<false><<<(N + TR - 1) / TR, 256, 0, stream>>>(
                csr, row_start, row_end, dinv, x, xh, Wt, b, gamma, beta, out, N);
        }
    } else {
        float* deg = (float*)d_ws;
        int n4 = N * DIM / 4;
        fill_zero4<<<(n4 + 255) / 256, 256, 0, stream>>>((float4*)out, n4);
        fill_zero<<<nb, 256, 0, stream>>>(deg, N);
        deg_kernel<<<(E + 255) / 256, 256, 0, stream>>>(ei, ew, deg, E);
        dinv_kernel<<<nb, 256, 0, stream>>>(deg, N);
        long long sthreads = (long long)E * 32;
        scatter_kernel<<<(int)((sthreads + 255) / 256), 256, 0, stream>>>(ei, ew, deg, x, out, E);
        gemm_ln_kernel<<<(N + TR - 1) / TR, 256, 0, stream>>>(x, W, b, gamma, beta, out, N);
    }
}

// Round 8
// 231.537 us; speedup vs baseline: 1.0322x; 1.0322x over previous
//
#include <hip/hip_runtime.h>
#include <hip/hip_fp16.h>
#include <math.h>

#define DIM 128
#define TR 32         // nodes per fused block
#define SA_STRIDE 136 // bf16 elements per sA row (128 + 8 pad, keeps 16B alignment)

#define DEG_SHIFT 42          // cnt in bits 42..63 of packed u64
#define DEG_SCALE 33554432.0f // 2^25 fixed-point scale for deg
#define DEG_MASK ((1ull << DEG_SHIFT) - 1)

typedef __attribute__((ext_vector_type(8))) short s16x8;   // 8 x 16-bit (bf16 or fp16)
typedef __attribute__((ext_vector_type(4))) float f32x4;

__device__ __forceinline__ ushort f2bf(float f) {
    union { float f; unsigned u; } v; v.f = f;
    unsigned u = v.u;
    return (ushort)((u + 0x7FFFu + ((u >> 16) & 1u)) >> 16);  // RNE
}

__device__ __forceinline__ ushort f2h(float f) {
    __half h = __float2half_rn(f);                 // v_cvt_f16_f32 (RNE)
    return *reinterpret_cast<ushort*>(&h);
}

__device__ __forceinline__ float h2f(ushort u) {
    __half_raw hr; hr.x = u;
    return __half2float(__half(hr));               // v_cvt_f32_f16
}

__global__ void fill_zero(float* p, int n) {
    int i = blockIdx.x * blockDim.x + threadIdx.x;
    if (i < n) p[i] = 0.f;
}

__global__ void fill_zero4(float4* p, int n4) {
    int i = blockIdx.x * blockDim.x + threadIdx.x;
    if (i < n4) p[i] = make_float4(0.f, 0.f, 0.f, 0.f);
}

// Init: Wt[n][k] = bf16(W[k][n]); zero cd (2N words); reset gctr.
// (xh conversion moved into count_deg — as a separate pass here it was ~13 us
// of serial streaming; under count_deg's atomic latency it is nearly free.)
__global__ void init_kernel(const float* __restrict__ W, ushort* __restrict__ Wt,
                            float* __restrict__ zbase, int nz, int* __restrict__ gctr) {
    int i = blockIdx.x * blockDim.x + threadIdx.x;
    if (i < 16384) {
        int k = i >> 7, n = i & 127;
        Wt[n * DIM + k] = f2bf(W[k * DIM + n]);
    }
    int z = i - 16384;
    if (z >= 0 && z < nz) zbase[z] = 0.f;
    if (i == 0) *gctr = 0;
}

// ONE u64 atomic per edge: cd[col] += (1<<42) | round(ew * 2^25); the returned
// old value's cnt field is this edge's arrival rank (makes csr_fill atomic-free).
// FUSED: grid-stride fp16 staging of x into xh (8 elems/group). The kernel is
// latency-bound on the random RMWs; the streaming conversion fills the idle BW
// between issuing the atomic and consuming its return value.
__global__ void count_deg_kernel(const int* __restrict__ ei, const float* __restrict__ ew,
                                 unsigned long long* __restrict__ cd,
                                 int* __restrict__ rank,
                                 const float* __restrict__ x, ushort* __restrict__ xh,
                                 int nxh, int E) {
    int e = blockIdx.x * blockDim.x + threadIdx.x;
    int nthreads = gridDim.x * blockDim.x;
    unsigned long long old = 0;
    bool valid = (e < E);
    if (valid) {
        int col = ei[E + e];
        unsigned long long pk = (1ull << DEG_SHIFT)
                              + (unsigned long long)(ew[e] * DEG_SCALE + 0.5f);
        old = atomicAdd(&cd[col], pk);             // issue early...
    }
    const float4* xs = (const float4*)x;
    for (int i = e; i < nxh; i += nthreads) {      // ...stream conversion while it flies
        float4 a = xs[i * 2], c = xs[i * 2 + 1];
        s16x8 h;
        h[0] = (short)f2h(a.x); h[1] = (short)f2h(a.y);
        h[2] = (short)f2h(a.z); h[3] = (short)f2h(a.w);
        h[4] = (short)f2h(c.x); h[5] = (short)f2h(c.y);
        h[6] = (short)f2h(c.z); h[7] = (short)f2h(c.w);
        *(s16x8*)&xh[i * 8] = h;                   // 16B store
    }
    if (valid) rank[e] = (int)(old >> DEG_SHIFT);  // ...consume late
}

// Segment allocation: wave-level inclusive scan of cnt, block-level combine in LDS,
// ONE atomicAdd per BLOCK on gctr (per-wave hot-line version serialized cross-XCD).
// Nodes within a block (256 consecutive ids) get contiguous, ordered segments.
// Writes row_start, row_end (= start + cnt) and dinv from the packed deg.
__global__ __launch_bounds__(256) void alloc_kernel(const unsigned long long* __restrict__ cd,
                                                    float* __restrict__ dinv,
                                                    int* __restrict__ row_start,
                                                    int* __restrict__ row_end,
                                                    int* __restrict__ gctr, int N) {
    __shared__ int wsum[4];
    __shared__ int sbase;
    int t = threadIdx.x;
    int i = blockIdx.x * 256 + t;
    int lane = t & 63;
    int w = t >> 6;
    unsigned long long p = (i < N) ? cd[i] : 0ull;
    int c = (int)(p >> DEG_SHIFT);
    int pre = c;
#pragma unroll
    for (int off = 1; off < 64; off <<= 1) {
        int v = __shfl_up(pre, off);
        if (lane >= off) pre += v;
    }
    if (lane == 63) wsum[w] = pre;
    __syncthreads();
    if (t == 0) sbase = atomicAdd(gctr, wsum[0] + wsum[1] + wsum[2] + wsum[3]);
    __syncthreads();
    int woff = 0;
#pragma unroll
    for (int k = 0; k < 3; ++k) if (w > k) woff += wsum[k];
    if (i < N) {
        int rs = sbase + woff + pre - c;   // exclusive prefix within block + block base
        row_start[i] = rs;
        row_end[i] = rs + c;
        float d = (float)(p & DEG_MASK) * (1.0f / DEG_SCALE);
        dinv[i] = d > 0.f ? rsqrtf(d) : 0.f;
    }
}

// CSR fill, ATOMIC-FREE: p = row_start[col] + rank[e]; csr[p] = {row, bits(dinv[row]*ew)}.
// Per edge: two random READS (row_start[col], dinv[row] — no RMW ping-pong) and one
// random 8B write. dinv[row] lives HERE, not in the gather (round 5: per-edge dinv
// load in the gather cost ~20 us via load-queue pressure / occupancy 46->38%).
__global__ void csr_fill_kernel(const int* __restrict__ ei, const float* __restrict__ ew,
                                const int* __restrict__ rank,
                                const int* __restrict__ row_start,
                                const float* __restrict__ dinv,
                                int2* __restrict__ csr, int E) {
    int e = blockIdx.x * blockDim.x + threadIdx.x;
    if (e < E) {
        int row = ei[e];
        int col = ei[E + e];
        int p = row_start[col] + rank[e];
        float w = dinv[row] * ew[e];
        csr[p] = make_int2(row, __float_as_int(w));
    }
}

// Fused: CSR gather -> LDS bf16 -> MFMA 32x128 @ 128x128 -> bias+LN+GELU+residual.
// 256 threads = 4 waves.
// Phase A (XH=true): 16 groups x 16 lanes, 2 nodes/group round-robin, 16B/lane
// (ushort8 = 8 fp16) -> one 256B row costs 16 lane-loads instead of 32. Round-7
// PMC showed the gather is VMEM-issue/latency bound (25% byte cut -> only 8%
// time cut), so instruction count is the lever. Pair lockstep waste ~1.27x vs
// quad's 1.55x. unroll 2 -> 4 chains/group = same chain density (8/32 lanes)
// that won at 46% occupancy. unroll 4 REGRESSED (occ 30%); extra per-edge load
// REGRESSED (occ 38%): exactly ONE row load per edge chain, VGPR <= ~56.
// Invalid slots predicated (clamp to csr[0], weight 0). Residual reads fp32 x.
// GEMM: wave w -> row-tile tm=w&1 (16 rows), col-tiles tn = 4*(w>>1)..+3 (64 cols).
template<bool XH>
__global__ __launch_bounds__(256) void gather_mfma_ln_kernel(
        const int2* __restrict__ csr, const int* __restrict__ row_start,
        const int* __restrict__ seg_end, const float* __restrict__ dinv,
        const float* __restrict__ x, const ushort* __restrict__ xh,
        const ushort* __restrict__ Wt, const float* __restrict__ b,
        const float* __restrict__ gamma, const float* __restrict__ beta,
        float* __restrict__ out, int N) {
    __shared__ ushort sA[TR * SA_STRIDE];  // 8.5 KB bf16 agg tile
    __shared__ float redS[4][16];
    __shared__ float redQ[4][16];

    const int tid  = threadIdx.x;
    const int lane = tid & 63;
    const int w    = tid >> 6;       // wave 0..3
    const int row0 = blockIdx.x * TR;

    if (XH) {
        // ---- Phase A: 16-lane groups, 2 nodes each, fp16 rows ----
        const int l16 = tid & 15;
        const int g16 = tid >> 4;    // 0..15
        const s16x8* xh8 = (const s16x8*)xh;
        int sidx[2], eidx[2];
        float dv[2];
        float accq[2][8];
        int maxlen = 0;
#pragma unroll
        for (int q = 0; q < 2; ++q) {
            int node = row0 + g16 * 2 + q;
            int ok = node < N;
            sidx[q] = ok ? row_start[node] : 0;
            eidx[q] = ok ? seg_end[node] : 0;
            dv[q]   = ok ? dinv[node] : 0.f;
#pragma unroll
            for (int e8 = 0; e8 < 8; ++e8) accq[q][e8] = 0.f;
            int len = eidx[q] - sidx[q];
            maxlen = len > maxlen ? len : maxlen;
        }
#pragma unroll 2
        for (int it = 0; it < maxlen; ++it) {
            int2 pk[2];
#pragma unroll
            for (int q = 0; q < 2; ++q) {
                int j = sidx[q] + it;
                pk[q] = csr[j < eidx[q] ? j : 0];   // predicated, always-valid addr
            }
#pragma unroll
            for (int q = 0; q < 2; ++q) {
                float wt = (sidx[q] + it < eidx[q]) ? __int_as_float(pk[q].y) : 0.f;
                s16x8 hv = xh8[(size_t)pk[q].x * 16 + l16];   // 16B/lane, 256B/row
#pragma unroll
                for (int e8 = 0; e8 < 8; ++e8)
                    accq[q][e8] += wt * h2f((ushort)hv[e8]);
            }
        }
#pragma unroll
        for (int q = 0; q < 2; ++q) {
            int r = g16 * 2 + q;
            s16x8 p8;
#pragma unroll
            for (int e8 = 0; e8 < 8; ++e8) p8[e8] = (short)f2bf(accq[q][e8] * dv[q]);
            *(s16x8*)&sA[r * SA_STRIDE + l16 * 8] = p8;   // ds_write_b128
        }
    } else {
        // ---- Phase A (fp32 fallback): 32-lane groups, 4 nodes each ----
        const int l32 = tid & 31;
        const int g32 = tid >> 5;
        const float4* xv = (const float4*)x;
        int sidx[4], eidx[4];
        float dv[4];
        float4 accq[4];
        int maxlen = 0;
#pragma unroll
        for (int q = 0; q < 4; ++q) {
            int node = row0 + g32 * 4 + q;
            int ok = node < N;
            sidx[q] = ok ? row_start[node] : 0;
            eidx[q] = ok ? seg_end[node] : 0;
            dv[q]   = ok ? dinv[node] : 0.f;
            accq[q] = make_float4(0.f, 0.f, 0.f, 0.f);
            int len = eidx[q] - sidx[q];
            maxlen = len > maxlen ? len : maxlen;
        }
#pragma unroll 2
        for (int it = 0; it < maxlen; ++it) {
            int2 pk[4];
#pragma unroll
            for (int q = 0; q < 4; ++q) {
                int j = sidx[q] + it;
                pk[q] = csr[j < eidx[q] ? j : 0];
            }
#pragma unroll
            for (int q = 0; q < 4; ++q) {
                float wt = (sidx[q] + it < eidx[q]) ? __int_as_float(pk[q].y) : 0.f;
                float4 v = xv[(size_t)pk[q].x * 32 + l32];
                accq[q].x += wt * v.x; accq[q].y += wt * v.y;
                accq[q].z += wt * v.z; accq[q].w += wt * v.w;
            }
        }
#pragma unroll
        for (int q = 0; q < 4; ++q) {
            int r = g32 * 4 + q;
            ushort4 p4;
            p4.x = f2bf(accq[q].x * dv[q]); p4.y = f2bf(accq[q].y * dv[q]);
            p4.z = f2bf(accq[q].z * dv[q]); p4.w = f2bf(accq[q].w * dv[q]);
            *(ushort4*)&sA[r * SA_STRIDE + l32 * 4] = p4;
        }
    }
    __syncthreads();

    // ---- Phase B: MFMA GEMM ----
    const int m16  = lane & 15;
    const int quad = lane >> 4;          // 0..3
    const int tm   = w & 1;              // row-tile
    const int tnb  = (w >> 1) * 4;       // first col-tile

    s16x8 afrag[4];
    const ushort* arow = &sA[(16 * tm + m16) * SA_STRIDE + quad * 8];
#pragma unroll
    for (int kb = 0; kb < 4; ++kb)
        afrag[kb] = *(const s16x8*)(arow + kb * 32);   // ds_read_b128

    f32x4 acc[4];
#pragma unroll
    for (int t = 0; t < 4; ++t) { acc[t][0] = 0.f; acc[t][1] = 0.f; acc[t][2] = 0.f; acc[t][3] = 0.f; }

#pragma unroll
    for (int kb = 0; kb < 4; ++kb) {
#pragma unroll
        for (int t = 0; t < 4; ++t) {
            const ushort* bp = Wt + (size_t)((tnb + t) * 16 + m16) * DIM + kb * 32 + quad * 8;
            s16x8 bfrag = *(const s16x8*)bp;            // global 16B, L1-resident
            acc[t] = __builtin_amdgcn_mfma_f32_16x16x32_bf16(afrag[kb], bfrag, acc[t], 0, 0, 0);
        }
    }

    // ---- bias (per col) before LN stats ----
    float gcol[4], becol[4];
#pragma unroll
    for (int t = 0; t < 4; ++t) {
        int col = (tnb + t) * 16 + m16;
        float bc = b[col];
        gcol[t]  = gamma[col];
        becol[t] = beta[col];
#pragma unroll
        for (int i = 0; i < 4; ++i) acc[t][i] += bc;
    }

    // ---- LN stats: rows 4*quad+i; reduce over this wave's 64 cols via quad shuffles ----
    float s[4], sq[4];
#pragma unroll
    for (int i = 0; i < 4; ++i) {
        s[i]  = acc[0][i] + acc[1][i] + acc[2][i] + acc[3][i];
        sq[i] = acc[0][i]*acc[0][i] + acc[1][i]*acc[1][i] + acc[2][i]*acc[2][i] + acc[3][i]*acc[3][i];
    }
#pragma unroll
    for (int off = 1; off <= 8; off <<= 1) {
#pragma unroll
        for (int i = 0; i < 4; ++i) {
            s[i]  += __shfl_xor(s[i], off);
            sq[i] += __shfl_xor(sq[i], off);
        }
    }
    if (m16 == 0) {
#pragma unroll
        for (int i = 0; i < 4; ++i) {
            redS[w][quad * 4 + i] = s[i];
            redQ[w][quad * 4 + i] = sq[i];
        }
    }
    __syncthreads();

    // ---- finish LN + GELU + residual, store ----
#pragma unroll
    for (int i = 0; i < 4; ++i) {
        int rloc = quad * 4 + i;
        float tot  = redS[w][rloc] + redS[w ^ 2][rloc];   // partner wave shares tm
        float totq = redQ[w][rloc] + redQ[w ^ 2][rloc];
        float mu   = tot * (1.0f / DIM);
        float var  = totq * (1.0f / DIM) - mu * mu;
        float rstd = rsqrtf(var + 1e-5f);
        int r = row0 + 16 * tm + rloc;
        if (r < N) {
#pragma unroll
            for (int t = 0; t < 4; ++t) {
                int col = (tnb + t) * 16 + m16;
                float l = (acc[t][i] - mu) * rstd * gcol[t] + becol[t];
                float g = 0.5f * l * (1.0f + erff(l * 0.70710678118654752f));
                out[(size_t)r * DIM + col] = x[(size_t)r * DIM + col] + g;
            }
        }
    }
}

// ---------------- fallback path (small workspace): atomic scatter + fp32 gemm_ln ----------------
__global__ void deg_kernel(const int* __restrict__ ei, const float* __restrict__ ew,
                           float* __restrict__ deg, int E) {
    int e = blockIdx.x * blockDim.x + threadIdx.x;
    if (e < E) atomicAdd(&deg[ei[E + e]], ew[e]);
}

__global__ void dinv_kernel(float* deg, int N) {
    int i = blockIdx.x * blockDim.x + threadIdx.x;
    if (i < N) {
        float d = deg[i];
        deg[i] = d > 0.f ? rsqrtf(d) : 0.f;
    }
}

__global__ void scatter_kernel(const int* __restrict__ ei, const float* __restrict__ ew,
                               const float* __restrict__ dinv, const float* __restrict__ x,
                               float* __restrict__ out, int E) {
    int t = blockIdx.x * blockDim.x + threadIdx.x;
    int e = t >> 5;
    if (e >= E) return;
    int lane = t & 31;
    int row = ei[e];
    int col = ei[E + e];
    float w = dinv[row] * ew[e] * dinv[col];
    float4 v = *(const float4*)(x + (size_t)row * DIM + (lane << 2));
    float* dst = out + (size_t)col * DIM + (lane << 2);
    atomicAdd(dst + 0, v.x * w);
    atomicAdd(dst + 1, v.y * w);
    atomicAdd(dst + 2, v.z * w);
    atomicAdd(dst + 3, v.w * w);
}

__global__ __launch_bounds__(256) void gemm_ln_kernel(const float* __restrict__ x,
                                                      const float* __restrict__ W,
                                                      const float* __restrict__ b,
                                                      const float* __restrict__ gamma,
                                                      const float* __restrict__ beta,
                                                      float* __restrict__ out, int N) {
    __shared__ float sT[DIM][TR + 4];
    const int tid = threadIdx.x;
    const int row0 = blockIdx.x * TR;
    {
        int r = tid >> 3;
        int c0 = (tid & 7) << 4;
        int rr = row0 + r; if (rr > N - 1) rr = N - 1;
        const float4* src = (const float4*)(out + (size_t)rr * DIM + c0);
#pragma unroll
        for (int i = 0; i < 4; ++i) {
            float4 v = src[i];
            int c = c0 + i * 4;
            sT[c + 0][r] = v.x; sT[c + 1][r] = v.y; sT[c + 2][r] = v.z; sT[c + 3][r] = v.w;
        }
    }
    __syncthreads();
    const int tx = tid & 31;
    const int ty = tid >> 5;
    float acc[4][4] = {};
    const float4* Wv = (const float4*)W;
#pragma unroll 4
    for (int k = 0; k < DIM; ++k) {
        float4 wv = Wv[k * 32 + tx];
        float4 a  = *(const float4*)(&sT[k][ty * 4]);
        acc[0][0] += a.x * wv.x; acc[0][1] += a.x * wv.y; acc[0][2] += a.x * wv.z; acc[0][3] += a.x * wv.w;
        acc[1][0] += a.y * wv.x; acc[1][1] += a.y * wv.y; acc[1][2] += a.y * wv.z; acc[1][3] += a.y * wv.w;
        acc[2][0] += a.z * wv.x; acc[2][1] += a.z * wv.y; acc[2][2] += a.z * wv.z; acc[2][3] += a.z * wv.w;
        acc[3][0] += a.w * wv.x; acc[3][1] += a.w * wv.y; acc[3][2] += a.w * wv.z; acc[3][3] += a.w * wv.w;
    }
    float4 b4 = ((const float4*)b)[tx];
#pragma unroll
    for (int i = 0; i < 4; ++i) {
        acc[i][0] += b4.x; acc[i][1] += b4.y; acc[i][2] += b4.z; acc[i][3] += b4.w;
    }
    float4 g4  = ((const float4*)gamma)[tx];
    float4 be4 = ((const float4*)beta)[tx];
#pragma unroll
    for (int i = 0; i < 4; ++i) {
        float s  = acc[i][0] + acc[i][1] + acc[i][2] + acc[i][3];
        float sq = acc[i][0]*acc[i][0] + acc[i][1]*acc[i][1] + acc[i][2]*acc[i][2] + acc[i][3]*acc[i][3];
#pragma unroll
        for (int off = 16; off > 0; off >>= 1) {
            s  += __shfl_xor(s, off);
            sq += __shfl_xor(sq, off);
        }
        float mu   = s * (1.0f / DIM);
        float var  = sq * (1.0f / DIM) - mu * mu;
        float rstd = rsqrtf(var + 1e-5f);
        int r = row0 + ty * 4 + i;
        if (r < N) {
            float4 xr = *(const float4*)(x + (size_t)r * DIM + tx * 4);
            float lg[4] = {g4.x, g4.y, g4.z, g4.w};
            float lb[4] = {be4.x, be4.y, be4.z, be4.w};
            float lx[4] = {xr.x, xr.y, xr.z, xr.w};
            float o[4];
#pragma unroll
            for (int c = 0; c < 4; ++c) {
                float l = (acc[i][c] - mu) * rstd * lg[c] + lb[c];
                float g = 0.5f * l * (1.0f + erff(l * 0.70710678118654752f));
                o[c] = lx[c] + g;
            }
            *(float4*)(out + (size_t)r * DIM + tx * 4) = make_float4(o[0], o[1], o[2], o[3]);
        }
    }
}

extern "C" void kernel_launch(void* const* d_in, const int* in_sizes, int n_in,
                              void* d_out, int out_size, void* d_ws, size_t ws_size,
                              hipStream_t stream) {
    const float* x     = (const float*)d_in[0];
    const int*   ei    = (const int*)d_in[1];    // [2, E] int32
    const float* ew    = (const float*)d_in[2];
    const float* W     = (const float*)d_in[3];
    const float* b     = (const float*)d_in[4];
    const float* gamma = (const float*)d_in[5];
    const float* beta  = (const float*)d_in[6];
    const int N = in_sizes[0] / DIM;
    const int E = in_sizes[2];
    float* out = (float*)d_out;

    const int nb = (N + 255) / 256;

    // ws words: Wt bf16[128*128] (8192) | cd u64[N] (2N) | dinv[N] | row_start[N] |
    //           row_end[N] | rank[E] | gctr[1] | pad16B | [xh ushort[N*128]] | csr int2[E]
    size_t hdr_words = 8192 + (size_t)5 * N + (size_t)E + 1;
    hdr_words = (hdr_words + 3) & ~(size_t)3;          // 16B align for xh stores
    size_t xh_words = (size_t)N * (DIM / 2);           // fp16 copy of x
    size_t need_basic = (hdr_words + (size_t)2 * E) * sizeof(float);
    size_t need_xh    = (hdr_words + xh_words + (size_t)2 * E) * sizeof(float);

    if (ws_size >= need_basic) {
        const bool use_xh = (ws_size >= need_xh);
        ushort* Wt         = (ushort*)d_ws;
        unsigned long long* cd = (unsigned long long*)((float*)d_ws + 8192);
        float*  dinv       = (float*)d_ws + 8192 + (size_t)2 * N;
        int*    row_start  = (int*)(dinv + N);
        int*    row_end    = row_start + N;
        int*    rank       = row_end + N;
        int*    gctr       = rank + E;
        ushort* xh         = (ushort*)((float*)d_ws + hdr_words);
        int2*   csr        = (int2*)((float*)d_ws + hdr_words + (use_xh ? xh_words : 0));

        int nxh = use_xh ? N * (DIM / 8) : 0;          // ushort8 groups to convert
        int initn = 16384 + 2 * N;
        init_kernel<<<(initn + 255) / 256, 256, 0, stream>>>(W, Wt, (float*)cd, 2 * N, gctr);
        count_deg_kernel<<<(E + 255) / 256, 256, 0, stream>>>(ei, ew, cd, rank, x, xh, nxh, E);
        alloc_kernel<<<nb, 256, 0, stream>>>(cd, dinv, row_start, row_end, gctr, N);
        csr_fill_kernel<<<(E + 255) / 256, 256, 0, stream>>>(ei, ew, rank, row_start, dinv, csr, E);

        if (use_xh) {
            gather_mfma_ln_kernel<true><<<(N + TR - 1) / TR, 256, 0, stream>>>(
                csr, row_start, row_end, dinv, x, xh, Wt, b, gamma, beta, out, N);
        } else {
            gather_mfma_ln_kernel<false><<<(N + TR - 1) / TR, 256, 0, stream>>>(
                csr, row_start, row_end, dinv, x, xh, Wt, b, gamma, beta, out, N);
        }
    } else {
        float* deg = (float*)d_ws;
        int n4 = N * DIM / 4;
        fill_zero4<<<(n4 + 255) / 256, 256, 0, stream>>>((float4*)out, n4);
        fill_zero<<<nb, 256, 0, stream>>>(deg, N);
        deg_kernel<<<(E + 255) / 256, 256, 0, stream>>>(ei, ew, deg, E);
        dinv_kernel<<<nb, 256, 0, stream>>>(deg, N);
        long long sthreads = (long long)E * 32;
        scatter_kernel<<<(int)((sthreads + 255) / 256), 256, 0, stream>>>(ei, ew, deg, x, out, E);
        gemm_ln_kernel<<<(N + TR - 1) / TR, 256, 0, stream>>>(x, W, b, gamma, beta, out, N);
    }
}

// Round 9
// 226.161 us; speedup vs baseline: 1.0568x; 1.0238x over previous
//
#include <hip/hip_runtime.h>
#include <hip/hip_fp16.h>
#include <math.h>

#define DIM 128
#define TR 32         // nodes per fused block
#define SA_STRIDE 136 // bf16 elements per sA row (128 + 8 pad, keeps 16B alignment)
#define CSR_CAP 1024  // LDS-staged csr entries per block (avg ~192; 59-sigma safe)

#define DEG_SHIFT 42          // cnt in bits 42..63 of packed u64
#define DEG_SCALE 33554432.0f // 2^25 fixed-point scale for deg
#define DEG_MASK ((1ull << DEG_SHIFT) - 1)

typedef __attribute__((ext_vector_type(8))) short s16x8;   // 8 x 16-bit (bf16 or fp16)
typedef __attribute__((ext_vector_type(4))) float f32x4;

__device__ __forceinline__ ushort f2bf(float f) {
    union { float f; unsigned u; } v; v.f = f;
    unsigned u = v.u;
    return (ushort)((u + 0x7FFFu + ((u >> 16) & 1u)) >> 16);  // RNE
}

__device__ __forceinline__ ushort f2h(float f) {
    __half h = __float2half_rn(f);                 // v_cvt_f16_f32 (RNE)
    return *reinterpret_cast<ushort*>(&h);
}

__device__ __forceinline__ float h2f(ushort u) {
    __half_raw hr; hr.x = u;
    return __half2float(__half(hr));               // v_cvt_f32_f16
}

__global__ void fill_zero(float* p, int n) {
    int i = blockIdx.x * blockDim.x + threadIdx.x;
    if (i < n) p[i] = 0.f;
}

__global__ void fill_zero4(float4* p, int n4) {
    int i = blockIdx.x * blockDim.x + threadIdx.x;
    if (i < n4) p[i] = make_float4(0.f, 0.f, 0.f, 0.f);
}

// Init: Wt[n][k] = bf16(W[k][n]); zero cd (2N words); reset gctr.
__global__ void init_kernel(const float* __restrict__ W, ushort* __restrict__ Wt,
                            float* __restrict__ zbase, int nz, int* __restrict__ gctr) {
    int i = blockIdx.x * blockDim.x + threadIdx.x;
    if (i < 16384) {
        int k = i >> 7, n = i & 127;
        Wt[n * DIM + k] = f2bf(W[k * DIM + n]);
    }
    int z = i - 16384;
    if (z >= 0 && z < nz) zbase[z] = 0.f;
    if (i == 0) *gctr = 0;
}

// ONE u64 atomic per edge: cd[col] += (1<<42) | round(ew * 2^25); the returned
// old value's cnt field is this edge's arrival rank (makes csr_fill atomic-free).
// Grid-stride fp16 staging of x into xh rides along (costs ~13 us of BW wherever
// it runs; kept here to avoid an extra dispatch).
__global__ void count_deg_kernel(const int* __restrict__ ei, const float* __restrict__ ew,
                                 unsigned long long* __restrict__ cd,
                                 int* __restrict__ rank,
                                 const float* __restrict__ x, ushort* __restrict__ xh,
                                 int nxh, int E) {
    int e = blockIdx.x * blockDim.x + threadIdx.x;
    int nthreads = gridDim.x * blockDim.x;
    unsigned long long old = 0;
    bool valid = (e < E);
    if (valid) {
        int col = ei[E + e];
        unsigned long long pk = (1ull << DEG_SHIFT)
                              + (unsigned long long)(ew[e] * DEG_SCALE + 0.5f);
        old = atomicAdd(&cd[col], pk);             // issue early...
    }
    const float4* xs = (const float4*)x;
    for (int i = e; i < nxh; i += nthreads) {      // ...stream conversion while it flies
        float4 a = xs[i * 2], c = xs[i * 2 + 1];
        s16x8 h;
        h[0] = (short)f2h(a.x); h[1] = (short)f2h(a.y);
        h[2] = (short)f2h(a.z); h[3] = (short)f2h(a.w);
        h[4] = (short)f2h(c.x); h[5] = (short)f2h(c.y);
        h[6] = (short)f2h(c.z); h[7] = (short)f2h(c.w);
        *(s16x8*)&xh[i * 8] = h;                   // 16B store
    }
    if (valid) rank[e] = (int)(old >> DEG_SHIFT);  // ...consume late
}

// Segment allocation: wave-level inclusive scan of cnt, block-level combine in LDS,
// ONE atomicAdd per BLOCK on gctr (per-wave hot-line version serialized cross-XCD).
// Nodes within a block (256 consecutive ids) get contiguous, ordered segments.
// Writes row_start, row_end (= start + cnt) and dinv from the packed deg.
__global__ __launch_bounds__(256) void alloc_kernel(const unsigned long long* __restrict__ cd,
                                                    float* __restrict__ dinv,
                                                    int* __restrict__ row_start,
                                                    int* __restrict__ row_end,
                                                    int* __restrict__ gctr, int N) {
    __shared__ int wsum[4];
    __shared__ int sbase;
    int t = threadIdx.x;
    int i = blockIdx.x * 256 + t;
    int lane = t & 63;
    int w = t >> 6;
    unsigned long long p = (i < N) ? cd[i] : 0ull;
    int c = (int)(p >> DEG_SHIFT);
    int pre = c;
#pragma unroll
    for (int off = 1; off < 64; off <<= 1) {
        int v = __shfl_up(pre, off);
        if (lane >= off) pre += v;
    }
    if (lane == 63) wsum[w] = pre;
    __syncthreads();
    if (t == 0) sbase = atomicAdd(gctr, wsum[0] + wsum[1] + wsum[2] + wsum[3]);
    __syncthreads();
    int woff = 0;
#pragma unroll
    for (int k = 0; k < 3; ++k) if (w > k) woff += wsum[k];
    if (i < N) {
        int rs = sbase + woff + pre - c;   // exclusive prefix within block + block base
        row_start[i] = rs;
        row_end[i] = rs + c;
        float d = (float)(p & DEG_MASK) * (1.0f / DEG_SCALE);
        dinv[i] = d > 0.f ? rsqrtf(d) : 0.f;
    }
}

// CSR fill, ATOMIC-FREE: p = row_start[col] + rank[e]; csr[p] = {row, bits(dinv[row]*ew)}.
// Per edge: two random READS (row_start[col], dinv[row] — no RMW ping-pong) and one
// random 8B write. dinv[row] lives HERE, not in the gather (round 5: per-edge dinv
// load in the gather cost ~20 us via load-queue pressure / occupancy 46->38%).
__global__ void csr_fill_kernel(const int* __restrict__ ei, const float* __restrict__ ew,
                                const int* __restrict__ rank,
                                const int* __restrict__ row_start,
                                const float* __restrict__ dinv,
                                int2* __restrict__ csr, int E) {
    int e = blockIdx.x * blockDim.x + threadIdx.x;
    if (e < E) {
        int row = ei[e];
        int col = ei[E + e];
        int p = row_start[col] + rank[e];
        float w = dinv[row] * ew[e];
        csr[p] = make_int2(row, __float_as_int(w));
    }
}

// Fused: CSR gather -> LDS bf16 -> MFMA 32x128 @ 128x128 -> bias+LN+GELU+residual.
// 256 threads = 4 waves.
// Phase A (XH=true): the block's csr range [S,T) is STAGED INTO LDS first
// (coalesced, one cooperative pass). This removes the csr->x dependent chain —
// round-8 PMC showed 1.54 TB/s on the L2-miss path (well under random-256B
// ceiling), i.e. still latency-bound on the two-level chain. With entries local,
// each 16-lane group iterates its 2 nodes' EXACT edge lists (no lockstep waste)
// with chunk-2 + unroll-2 -> 4 independent x-row loads in flight per group.
// Fallback (range > CSR_CAP, impossible for this distribution but required for
// general inputs): round-8 streaming round-robin.
// Rules learned: exactly ONE row load per edge chain; VGPR <= 64 (occupancy 8
// waves/SIMD); 16B/lane loads.
// GEMM: wave w -> row-tile tm=w&1 (16 rows), col-tiles tn = 4*(w>>1)..+3 (64 cols).
template<bool XH>
__global__ __launch_bounds__(256) void gather_mfma_ln_kernel(
        const int2* __restrict__ csr, const int* __restrict__ row_start,
        const int* __restrict__ seg_end, const float* __restrict__ dinv,
        const float* __restrict__ x, const ushort* __restrict__ xh,
        const ushort* __restrict__ Wt, const float* __restrict__ b,
        const float* __restrict__ gamma, const float* __restrict__ beta,
        float* __restrict__ out, int N) {
    __shared__ ushort sA[TR * SA_STRIDE];  // 8.5 KB bf16 agg tile
    __shared__ int2 sCsr[CSR_CAP];         // 8 KB staged csr segment
    __shared__ float redS[4][16];
    __shared__ float redQ[4][16];

    const int tid  = threadIdx.x;
    const int lane = tid & 63;
    const int w    = tid >> 6;       // wave 0..3
    const int row0 = blockIdx.x * TR;

    if (XH) {
        // ---- stage the block's csr range into LDS ----
        int lastNode = row0 + TR - 1; if (lastNode > N - 1) lastNode = N - 1;
        const int S = row_start[row0];
        const int T = seg_end[lastNode];
        const int M = T - S;
        const bool useLds = (M <= CSR_CAP);
        if (useLds) {
            for (int i = tid; i < M; i += 256) sCsr[i] = csr[S + i];
        }
        __syncthreads();

        // ---- Phase A: 16-lane groups, 2 nodes each, fp16 rows ----
        const int l16 = tid & 15;
        const int g16 = tid >> 4;    // 0..15
        const s16x8* xh8 = (const s16x8*)xh;
        int sidx[2], eidx[2];
        float dv[2];
        float accq[2][8];
#pragma unroll
        for (int q = 0; q < 2; ++q) {
            int node = row0 + g16 * 2 + q;
            int ok = node < N;
            sidx[q] = ok ? row_start[node] : 0;
            eidx[q] = ok ? seg_end[node] : 0;
            dv[q]   = ok ? dinv[node] : 0.f;
#pragma unroll
            for (int e8 = 0; e8 < 8; ++e8) accq[q][e8] = 0.f;
        }

        if (useLds) {
            // exact-length loops; entries from LDS (no global dependency);
            // chunk-2 + unroll-2 -> 4 independent row loads in flight per group
#pragma unroll
            for (int q = 0; q < 2; ++q) {
                int sL = sidx[q] - S, eL = eidx[q] - S;
#pragma unroll 2
                for (int j = sL; j < eL; j += 2) {
                    int2 e0 = sCsr[j];
                    bool v1 = (j + 1) < eL;
                    int2 e1 = sCsr[v1 ? j + 1 : j];
                    float w0 = __int_as_float(e0.y);
                    float w1 = v1 ? __int_as_float(e1.y) : 0.f;
                    s16x8 r0 = xh8[(size_t)e0.x * 16 + l16];   // independent 16B loads
                    s16x8 r1 = xh8[(size_t)e1.x * 16 + l16];
#pragma unroll
                    for (int e8 = 0; e8 < 8; ++e8) {
                        accq[q][e8] += w0 * h2f((ushort)r0[e8]);
                        accq[q][e8] += w1 * h2f((ushort)r1[e8]);
                    }
                }
            }
        } else {
            // streaming fallback: round-robin lockstep over the 2 nodes
            int maxlen = 0;
#pragma unroll
            for (int q = 0; q < 2; ++q) {
                int len = eidx[q] - sidx[q];
                maxlen = len > maxlen ? len : maxlen;
            }
#pragma unroll 2
            for (int it = 0; it < maxlen; ++it) {
                int2 pk[2];
#pragma unroll
                for (int q = 0; q < 2; ++q) {
                    int j = sidx[q] + it;
                    pk[q] = csr[j < eidx[q] ? j : 0];
                }
#pragma unroll
                for (int q = 0; q < 2; ++q) {
                    float wt = (sidx[q] + it < eidx[q]) ? __int_as_float(pk[q].y) : 0.f;
                    s16x8 hv = xh8[(size_t)pk[q].x * 16 + l16];
#pragma unroll
                    for (int e8 = 0; e8 < 8; ++e8)
                        accq[q][e8] += wt * h2f((ushort)hv[e8]);
                }
            }
        }
#pragma unroll
        for (int q = 0; q < 2; ++q) {
            int r = g16 * 2 + q;
            s16x8 p8;
#pragma unroll
            for (int e8 = 0; e8 < 8; ++e8) p8[e8] = (short)f2bf(accq[q][e8] * dv[q]);
            *(s16x8*)&sA[r * SA_STRIDE + l16 * 8] = p8;   // ds_write_b128
        }
    } else {
        // ---- Phase A (fp32 fallback): 32-lane groups, 4 nodes each ----
        const int l32 = tid & 31;
        const int g32 = tid >> 5;
        const float4* xv = (const float4*)x;
        int sidx[4], eidx[4];
        float dv[4];
        float4 accq[4];
        int maxlen = 0;
#pragma unroll
        for (int q = 0; q < 4; ++q) {
            int node = row0 + g32 * 4 + q;
            int ok = node < N;
            sidx[q] = ok ? row_start[node] : 0;
            eidx[q] = ok ? seg_end[node] : 0;
            dv[q]   = ok ? dinv[node] : 0.f;
            accq[q] = make_float4(0.f, 0.f, 0.f, 0.f);
            int len = eidx[q] - sidx[q];
            maxlen = len > maxlen ? len : maxlen;
        }
#pragma unroll 2
        for (int it = 0; it < maxlen; ++it) {
            int2 pk[4];
#pragma unroll
            for (int q = 0; q < 4; ++q) {
                int j = sidx[q] + it;
                pk[q] = csr[j < eidx[q] ? j : 0];
            }
#pragma unroll
            for (int q = 0; q < 4; ++q) {
                float wt = (sidx[q] + it < eidx[q]) ? __int_as_float(pk[q].y) : 0.f;
                float4 v = xv[(size_t)pk[q].x * 32 + l32];
                accq[q].x += wt * v.x; accq[q].y += wt * v.y;
                accq[q].z += wt * v.z; accq[q].w += wt * v.w;
            }
        }
#pragma unroll
        for (int q = 0; q < 4; ++q) {
            int r = g32 * 4 + q;
            ushort4 p4;
            p4.x = f2bf(accq[q].x * dv[q]); p4.y = f2bf(accq[q].y * dv[q]);
            p4.z = f2bf(accq[q].z * dv[q]); p4.w = f2bf(accq[q].w * dv[q]);
            *(ushort4*)&sA[r * SA_STRIDE + l32 * 4] = p4;
        }
    }
    __syncthreads();

    // ---- Phase B: MFMA GEMM ----
    const int m16  = lane & 15;
    const int quad = lane >> 4;          // 0..3
    const int tm   = w & 1;              // row-tile
    const int tnb  = (w >> 1) * 4;       // first col-tile

    s16x8 afrag[4];
    const ushort* arow = &sA[(16 * tm + m16) * SA_STRIDE + quad * 8];
#pragma unroll
    for (int kb = 0; kb < 4; ++kb)
        afrag[kb] = *(const s16x8*)(arow + kb * 32);   // ds_read_b128

    f32x4 acc[4];
#pragma unroll
    for (int t = 0; t < 4; ++t) { acc[t][0] = 0.f; acc[t][1] = 0.f; acc[t][2] = 0.f; acc[t][3] = 0.f; }

#pragma unroll
    for (int kb = 0; kb < 4; ++kb) {
#pragma unroll
        for (int t = 0; t < 4; ++t) {
            const ushort* bp = Wt + (size_t)((tnb + t) * 16 + m16) * DIM + kb * 32 + quad * 8;
            s16x8 bfrag = *(const s16x8*)bp;            // global 16B, L1-resident
            acc[t] = __builtin_amdgcn_mfma_f32_16x16x32_bf16(afrag[kb], bfrag, acc[t], 0, 0, 0);
        }
    }

    // ---- bias (per col) before LN stats ----
    float gcol[4], becol[4];
#pragma unroll
    for (int t = 0; t < 4; ++t) {
        int col = (tnb + t) * 16 + m16;
        float bc = b[col];
        gcol[t]  = gamma[col];
        becol[t] = beta[col];
#pragma unroll
        for (int i = 0; i < 4; ++i) acc[t][i] += bc;
    }

    // ---- LN stats: rows 4*quad+i; reduce over this wave's 64 cols via quad shuffles ----
    float s[4], sq[4];
#pragma unroll
    for (int i = 0; i < 4; ++i) {
        s[i]  = acc[0][i] + acc[1][i] + acc[2][i] + acc[3][i];
        sq[i] = acc[0][i]*acc[0][i] + acc[1][i]*acc[1][i] + acc[2][i]*acc[2][i] + acc[3][i]*acc[3][i];
    }
#pragma unroll
    for (int off = 1; off <= 8; off <<= 1) {
#pragma unroll
        for (int i = 0; i < 4; ++i) {
            s[i]  += __shfl_xor(s[i], off);
            sq[i] += __shfl_xor(sq[i], off);
        }
    }
    if (m16 == 0) {
#pragma unroll
        for (int i = 0; i < 4; ++i) {
            redS[w][quad * 4 + i] = s[i];
            redQ[w][quad * 4 + i] = sq[i];
        }
    }
    __syncthreads();

    // ---- finish LN + GELU + residual, store ----
#pragma unroll
    for (int i = 0; i < 4; ++i) {
        int rloc = quad * 4 + i;
        float tot  = redS[w][rloc] + redS[w ^ 2][rloc];   // partner wave shares tm
        float totq = redQ[w][rloc] + redQ[w ^ 2][rloc];
        float mu   = tot * (1.0f / DIM);
        float var  = totq * (1.0f / DIM) - mu * mu;
        float rstd = rsqrtf(var + 1e-5f);
        int r = row0 + 16 * tm + rloc;
        if (r < N) {
#pragma unroll
            for (int t = 0; t < 4; ++t) {
                int col = (tnb + t) * 16 + m16;
                float l = (acc[t][i] - mu) * rstd * gcol[t] + becol[t];
                float g = 0.5f * l * (1.0f + erff(l * 0.70710678118654752f));
                out[(size_t)r * DIM + col] = x[(size_t)r * DIM + col] + g;
            }
        }
    }
}

// ---------------- fallback path (small workspace): atomic scatter + fp32 gemm_ln ----------------
__global__ void deg_kernel(const int* __restrict__ ei, const float* __restrict__ ew,
                           float* __restrict__ deg, int E) {
    int e = blockIdx.x * blockDim.x + threadIdx.x;
    if (e < E) atomicAdd(&deg[ei[E + e]], ew[e]);
}

__global__ void dinv_kernel(float* deg, int N) {
    int i = blockIdx.x * blockDim.x + threadIdx.x;
    if (i < N) {
        float d = deg[i];
        deg[i] = d > 0.f ? rsqrtf(d) : 0.f;
    }
}

__global__ void scatter_kernel(const int* __restrict__ ei, const float* __restrict__ ew,
                               const float* __restrict__ dinv, const float* __restrict__ x,
                               float* __restrict__ out, int E) {
    int t = blockIdx.x * blockDim.x + threadIdx.x;
    int e = t >> 5;
    if (e >= E) return;
    int lane = t & 31;
    int row = ei[e];
    int col = ei[E + e];
    float w = dinv[row] * ew[e] * dinv[col];
    float4 v = *(const float4*)(x + (size_t)row * DIM + (lane << 2));
    float* dst = out + (size_t)col * DIM + (lane << 2);
    atomicAdd(dst + 0, v.x * w);
    atomicAdd(dst + 1, v.y * w);
    atomicAdd(dst + 2, v.z * w);
    atomicAdd(dst + 3, v.w * w);
}

__global__ __launch_bounds__(256) void gemm_ln_kernel(const float* __restrict__ x,
                                                      const float* __restrict__ W,
                                                      const float* __restrict__ b,
                                                      const float* __restrict__ gamma,
                                                      const float* __restrict__ beta,
                                                      float* __restrict__ out, int N) {
    __shared__ float sT[DIM][TR + 4];
    const int tid = threadIdx.x;
    const int row0 = blockIdx.x * TR;
    {
        int r = tid >> 3;
        int c0 = (tid & 7) << 4;
        int rr = row0 + r; if (rr > N - 1) rr = N - 1;
        const float4* src = (const float4*)(out + (size_t)rr * DIM + c0);
#pragma unroll
        for (int i = 0; i < 4; ++i) {
            float4 v = src[i];
            int c = c0 + i * 4;
            sT[c + 0][r] = v.x; sT[c + 1][r] = v.y; sT[c + 2][r] = v.z; sT[c + 3][r] = v.w;
        }
    }
    __syncthreads();
    const int tx = tid & 31;
    const int ty = tid >> 5;
    float acc[4][4] = {};
    const float4* Wv = (const float4*)W;
#pragma unroll 4
    for (int k = 0; k < DIM; ++k) {
        float4 wv = Wv[k * 32 + tx];
        float4 a  = *(const float4*)(&sT[k][ty * 4]);
        acc[0][0] += a.x * wv.x; acc[0][1] += a.x * wv.y; acc[0][2] += a.x * wv.z; acc[0][3] += a.x * wv.w;
        acc[1][0] += a.y * wv.x; acc[1][1] += a.y * wv.y; acc[1][2] += a.y * wv.z; acc[1][3] += a.y * wv.w;
        acc[2][0] += a.z * wv.x; acc[2][1] += a.z * wv.y; acc[2][2] += a.z * wv.z; acc[2][3] += a.z * wv.w;
        acc[3][0] += a.w * wv.x; acc[3][1] += a.w * wv.y; acc[3][2] += a.w * wv.z; acc[3][3] += a.w * wv.w;
    }
    float4 b4 = ((const float4*)b)[tx];
#pragma unroll
    for (int i = 0; i < 4; ++i) {
        acc[i][0] += b4.x; acc[i][1] += b4.y; acc[i][2] += b4.z; acc[i][3] += b4.w;
    }
    float4 g4  = ((const float4*)gamma)[tx];
    float4 be4 = ((const float4*)beta)[tx];
#pragma unroll
    for (int i = 0; i < 4; ++i) {
        float s  = acc[i][0] + acc[i][1] + acc[i][2] + acc[i][3];
        float sq = acc[i][0]*acc[i][0] + acc[i][1]*acc[i][1] + acc[i][2]*acc[i][2] + acc[i][3]*acc[i][3];
#pragma unroll
        for (int off = 16; off > 0; off >>= 1) {
            s  += __shfl_xor(s, off);
            sq += __shfl_xor(sq, off);
        }
        float mu   = s * (1.0f / DIM);
        float var  = sq * (1.0f / DIM) - mu * mu;
        float rstd = rsqrtf(var + 1e-5f);
        int r = row0 + ty * 4 + i;
        if (r < N) {
            float4 xr = *(const float4*)(x + (size_t)r * DIM + tx * 4);
            float lg[4] = {g4.x, g4.y, g4.z, g4.w};
            float lb[4] = {be4.x, be4.y, be4.z, be4.w};
            float lx[4] = {xr.x, xr.y, xr.z, xr.w};
            float o[4];
#pragma unroll
            for (int c = 0; c < 4; ++c) {
                float l = (acc[i][c] - mu) * rstd * lg[c] + lb[c];
                float g = 0.5f * l * (1.0f + erff(l * 0.70710678118654752f));
                o[c] = lx[c] + g;
            }
            *(float4*)(out + (size_t)r * DIM + tx * 4) = make_float4(o[0], o[1], o[2], o[3]);
        }
    }
}

extern "C" void kernel_launch(void* const* d_in, const int* in_sizes, int n_in,
                              void* d_out, int out_size, void* d_ws, size_t ws_size,
                              hipStream_t stream) {
    const float* x     = (const float*)d_in[0];
    const int*   ei    = (const int*)d_in[1];    // [2, E] int32
    const float* ew    = (const float*)d_in[2];
    const float* W     = (const float*)d_in[3];
    const float* b     = (const float*)d_in[4];
    const float* gamma = (const float*)d_in[5];
    const float* beta  = (const float*)d_in[6];
    const int N = in_sizes[0] / DIM;
    const int E = in_sizes[2];
    float* out = (float*)d_out;

    const int nb = (N + 255) / 256;

    // ws words: Wt bf16[128*128] (8192) | cd u64[N] (2N) | dinv[N] | row_start[N] |
    //           row_end[N] | rank[E] | gctr[1] | pad16B | [xh ushort[N*128]] | csr int2[E]
    size_t hdr_words = 8192 + (size_t)5 * N + (size_t)E + 1;
    hdr_words = (hdr_words + 3) & ~(size_t)3;          // 16B align for xh stores
    size_t xh_words = (size_t)N * (DIM / 2);           // fp16 copy of x
    size_t need_basic = (hdr_words + (size_t)2 * E) * sizeof(float);
    size_t need_xh    = (hdr_words + xh_words + (size_t)2 * E) * sizeof(float);

    if (ws_size >= need_basic) {
        const bool use_xh = (ws_size >= need_xh);
        ushort* Wt         = (ushort*)d_ws;
        unsigned long long* cd = (unsigned long long*)((float*)d_ws + 8192);
        float*  dinv       = (float*)d_ws + 8192 + (size_t)2 * N;
        int*    row_start  = (int*)(dinv + N);
        int*    row_end    = row_start + N;
        int*    rank       = row_end + N;
        int*    gctr       = rank + E;
        ushort* xh         = (ushort*)((float*)d_ws + hdr_words);
        int2*   csr        = (int2*)((float*)d_ws + hdr_words + (use_xh ? xh_words : 0));

        int nxh = use_xh ? N * (DIM / 8) : 0;          // ushort8 groups to convert
        int initn = 16384 + 2 * N;
        init_kernel<<<(initn + 255) / 256, 256, 0, stream>>>(W, Wt, (float*)cd, 2 * N, gctr);
        count_deg_kernel<<<(E + 255) / 256, 256, 0, stream>>>(ei, ew, cd, rank, x, xh, nxh, E);
        alloc_kernel<<<nb, 256, 0, stream>>>(cd, dinv, row_start, row_end, gctr, N);
        csr_fill_kernel<<<(E + 255) / 256, 256, 0, stream>>>(ei, ew, rank, row_start, dinv, csr, E);

        if (use_xh) {
            gather_mfma_ln_kernel<true><<<(N + TR - 1) / TR, 256, 0, stream>>>(
                csr, row_start, row_end, dinv, x, xh, Wt, b, gamma, beta, out, N);
        } else {
            gather_mfma_ln_kernel<false><<<(N + TR - 1) / TR, 256, 0, stream>>>(
                csr, row_start, row_end, dinv, x, xh, Wt, b, gamma, beta, out, N);
        }
    } else {
        float* deg = (float*)d_ws;
        int n4 = N * DIM / 4;
        fill_zero4<<<(n4 + 255) / 256, 256, 0, stream>>>((float4*)out, n4);
        fill_zero<<<nb, 256, 0, stream>>>(deg, N);
        deg_kernel<<<(E + 255) / 256, 256, 0, stream>>>(ei, ew, deg, E);
        dinv_kernel<<<nb, 256, 0, stream>>>(deg, N);
        long long sthreads = (long long)E * 32;
        scatter_kernel<<<(int)((sthreads + 255) / 256), 256, 0, stream>>>(ei, ew, deg, x, out, E);
        gemm_ln_kernel<<<(N + TR - 1) / TR, 256, 0, stream>>>(x, W, b, gamma, beta, out, N);
    }
}